// Round 1
// 913.400 us; speedup vs baseline: 1.4282x; 1.4282x over previous
//
#include <hip/hip_runtime.h>
#include <hip/hip_bf16.h>

#define BB 1024
#define LL 50
#define HH 256
#define AA 100
#define NN 100000
#define NM1 99999

typedef short short8 __attribute__((ext_vector_type(8)));
typedef float f32x4 __attribute__((ext_vector_type(4)));

__device__ __forceinline__ float wave_sum(float v) {
#pragma unroll
  for (int off = 32; off; off >>= 1) v += __shfl_xor(v, off, 64);
  return v;
}
__device__ __forceinline__ float wave_max(float v) {
#pragma unroll
  for (int off = 32; off; off >>= 1) v = fmaxf(v, __shfl_xor(v, off, 64));
  return v;
}
__device__ __forceinline__ short f2bf(float f) {
  union { __hip_bfloat16 h; short s; } u;
  u.h = __float2bfloat16(f);
  return u.s;
}

// ---------------------------------------------------------------------------
// Kernel A: one block per session b. Fuses gather, Q/K, affinity, softmax,
// attention pooling, last-item concat, and the final linear layer.
// Outputs: affinity [B,L,L] to d_out tail, final_rep [B,H] as BF16 to d_ws
// (consumed by the MFMA scores GEMM).
// ---------------------------------------------------------------------------
__global__ __launch_bounds__(256) void session_kernel(
    const int* __restrict__ inputs, const float* __restrict__ masks,
    const float* __restrict__ emb, const float* __restrict__ Qw,
    const float* __restrict__ Kw, const float* __restrict__ lin_w,
    const float* __restrict__ lin_b, float* __restrict__ out_aff,
    short* __restrict__ frb) {
  __shared__ float s_x[LL][HH];                 // 51200 B
  __shared__ __hip_bfloat16 s_q[LL][AA + 4];    // 10400 B  Q[l][a]
  __shared__ __hip_bfloat16 s_kT[AA][LL + 2];   // 10400 B  K^T[a][m]
  __shared__ float s_mask[LL];
  __shared__ int s_idx[LL];
  __shared__ float s_row[LL];
  __shared__ float s_p[LL];
  __shared__ float s_cat[2 * HH];
  __shared__ int s_last;

  const int b = blockIdx.x;
  const int tid = threadIdx.x;

  if (tid < LL) {
    s_idx[tid] = inputs[b * LL + tid];
    s_mask[tid] = masks[b * LL + tid];
  }
  __syncthreads();

  // ---- gather x = emb[inputs[b]] into LDS (float4 coalesced) ----
  for (int u = tid; u < LL * (HH / 4); u += 256) {
    int l = u >> 6, c = u & 63;
    ((float4*)&s_x[l][0])[c] = ((const float4*)(emb + (size_t)s_idx[l] * HH))[c];
  }
  __syncthreads();

  // ---- Q,K: thread owns one output column (a). k-outer, l-inner, acc in regs.
  if (tid < 2 * AA) {
    const float* W = (tid < AA) ? (Qw + tid * HH) : (Kw + (tid - AA) * HH);
    float acc[LL];
#pragma unroll
    for (int l = 0; l < LL; ++l) acc[l] = 0.f;
    for (int k0 = 0; k0 < HH; k0 += 8) {
      float4 w0 = *(const float4*)(W + k0);
      float4 w1 = *(const float4*)(W + k0 + 4);
#pragma unroll
      for (int l = 0; l < LL; ++l) {
        float4 x0 = *(const float4*)&s_x[l][k0];
        float4 x1 = *(const float4*)&s_x[l][k0 + 4];
        acc[l] += w0.x * x0.x + w0.y * x0.y + w0.z * x0.z + w0.w * x0.w +
                  w1.x * x1.x + w1.y * x1.y + w1.z * x1.z + w1.w * x1.w;
      }
    }
    if (tid < AA) {
#pragma unroll
      for (int l = 0; l < LL; ++l)
        s_q[l][tid] = __float2bfloat16(1.f / (1.f + expf(-acc[l])));
    } else {
      const int a = tid - AA;
#pragma unroll
      for (int l = 0; l < LL; ++l)
        s_kT[a][l] = __float2bfloat16(1.f / (1.f + expf(-acc[l])));
    }
  }
  __syncthreads();

  // ---- affinity[l][m] = Q[l]·K[m] / 10; write raw (incl. diagonal) to out,
  //      accumulate masked row sums. Wave w handles rows l = w, w+4, ...
  {
    const int wv = tid >> 6;
    const int m = tid & 63;
    for (int l = wv; l < LL; l += 4) {
      float acc = 0.f;
      if (m < LL) {
#pragma unroll 10
        for (int a = 0; a < AA; ++a)
          acc += __bfloat162float(s_q[l][a]) * __bfloat162float(s_kT[a][m]);
      }
      const float aff = acc * 0.1f;  // 1/sqrt(A), A=100
      if (m < LL) out_aff[(size_t)b * (LL * LL) + l * LL + m] = aff;
      const float am = (m < LL && m != l) ? aff * s_mask[m] : 0.f;
      const float tot = wave_sum(am);
      if (m == 0) s_row[l] = tot * s_mask[l];
    }
  }
  __syncthreads();

  // ---- softmax over l (stable), mask, renormalize; last item id. One wave.
  if (tid < 64) {
    const int l = tid;
    const float mk = (l < LL) ? s_mask[l] : 0.f;
    const float v = (l < LL) ? s_row[l] : -3.4e38f;
    const float mx = wave_max(v);
    const float e = (l < LL) ? expf(v - mx) : 0.f;
    const float s1 = wave_sum(e);
    float p = e / s1 * mk;
    const float s2 = wave_sum(p);
    p /= s2;
    if (l < LL) s_p[l] = p;
    const float cnt = wave_sum(mk);
    if (l == 0) s_last = s_idx[(int)(cnt + 0.5f) - 1];
  }
  __syncthreads();

  // ---- att_final (weighted sum of x) + last_emb -> concat in LDS ----
  {
    const int h = tid;
    float acc = 0.f;
#pragma unroll
    for (int l = 0; l < LL; ++l) acc += s_p[l] * s_x[l][h];
    s_cat[h] = acc;
    s_cat[HH + h] = emb[(size_t)s_last * HH + h];
  }
  __syncthreads();

  // ---- final_rep[h] = lin_b[h] + cat · lin_w[h,:]  -> BF16 to workspace ----
  {
    const int h = tid;
    float acc = lin_b[h];
    const float4* lw = (const float4*)(lin_w + (size_t)h * (2 * HH));
#pragma unroll 16
    for (int j = 0; j < (2 * HH) / 4; ++j) {
      float4 w = lw[j];
      float4 cv = *(const float4*)&s_cat[j * 4];
      acc += w.x * cv.x + w.y * cv.y + w.z * cv.z + w.w * cv.w;
    }
    frb[(size_t)b * HH + h] = f2bf(acc);
  }
}

// ---------------------------------------------------------------------------
// Kernel B: scores[m][n] = FR[m,:] · emb[1+n,:]   (M=1024, N=99999, K=256)
// BF16 MFMA GEMM, 128x128 tile, 4 waves (2x2), 4x4 frags of 16x16x32.
// Full K=256 staged once in LDS (A 64 KB + B 64 KB = 128 KB), XOR-swizzled
// (byte ^= (row&7)<<4) so stride-512B ds_read_b128 is ~conflict-free.
// emb is converted fp32->bf16 on the fly during staging (L3 caches re-reads).
// Grid swizzle: 8 M-blocks sharing one emb tile run consecutively on the
// same XCD (wgid%8 == xcd), so the B tile stays in that XCD's L2.
// ---------------------------------------------------------------------------
#define NBLK 782  // ceil(99999/128)
__global__ __launch_bounds__(256) void scores_kernel(
    const short* __restrict__ frb, const float* __restrict__ emb,
    float* __restrict__ out) {
  __shared__ short As[128 * 256];  // 64 KB, swizzled
  __shared__ short Bs[128 * 256];  // 64 KB, swizzled

  const int tid = threadIdx.x;
  const int wg = blockIdx.x;
  // bijective XCD chunking: 6256 = 8 * 782; p runs m-fastest within an XCD
  const int p = (wg & 7) * NBLK + (wg >> 3);
  const int m0 = (p & 7) * 128;
  const int n0 = (p >> 3) * 128;

  // ---- stage A: fr_bf16 rows m0..m0+127, 16B chunks, coalesced ----
#pragma unroll
  for (int i = 0; i < 16; ++i) {
    const int idx = tid + i * 256;
    const int r = idx >> 5, c = idx & 31;
    int byte = ((r << 9) | (c << 4)) ^ ((r & 7) << 4);
    *(short8*)((char*)As + byte) =
        *(const short8*)(frb + (((size_t)(m0 + r)) << 8) + (c << 3));
  }
  // ---- stage B: emb rows 1+n0..1+n0+127 (clamped), cvt fp32->bf16 ----
#pragma unroll
  for (int i = 0; i < 16; ++i) {
    const int idx = tid + i * 256;
    const int r = idx >> 5, c = idx & 31;
    int er = 1 + n0 + r;
    if (er > NM1) er = NM1;
    const float* s = emb + (((size_t)er) << 8) + (c << 3);
    const float4 f0 = *(const float4*)s;
    const float4 f1 = *(const float4*)(s + 4);
    short8 v;
    v[0] = f2bf(f0.x); v[1] = f2bf(f0.y); v[2] = f2bf(f0.z); v[3] = f2bf(f0.w);
    v[4] = f2bf(f1.x); v[5] = f2bf(f1.y); v[6] = f2bf(f1.z); v[7] = f2bf(f1.w);
    int byte = ((r << 9) | (c << 4)) ^ ((r & 7) << 4);
    *(short8*)((char*)Bs + byte) = v;
  }
  __syncthreads();

  const int lane = tid & 63;
  const int wv = tid >> 6;           // wave 0..3
  const int wr = wv >> 1, wc = wv & 1;  // 2x2 wave grid, each wave 64x64
  const int l15 = lane & 15, lg = lane >> 4;

  f32x4 acc[4][4];
#pragma unroll
  for (int fm = 0; fm < 4; ++fm)
#pragma unroll
    for (int fn = 0; fn < 4; ++fn) acc[fm][fn] = (f32x4)(0.f);

#pragma unroll
  for (int ks = 0; ks < 8; ++ks) {
    const int kb = ks * 64 + (lg << 4);
    short8 af[4], bf[4];
#pragma unroll
    for (int f = 0; f < 4; ++f) {
      const int Ra = wr * 64 + f * 16 + l15;
      const int ba = ((Ra << 9) + kb) ^ ((Ra & 7) << 4);
      af[f] = *(const short8*)((const char*)As + ba);
      const int Rb = wc * 64 + f * 16 + l15;
      const int bb = ((Rb << 9) + kb) ^ ((Rb & 7) << 4);
      bf[f] = *(const short8*)((const char*)Bs + bb);
    }
#pragma unroll
    for (int fm = 0; fm < 4; ++fm)
#pragma unroll
      for (int fn = 0; fn < 4; ++fn)
        acc[fm][fn] = __builtin_amdgcn_mfma_f32_16x16x32_bf16(
            af[fm], bf[fn], acc[fm][fn], 0, 0, 0);
  }

  // ---- epilogue: C/D layout col=lane&15, row=(lane>>4)*4+reg ----
#pragma unroll
  for (int fm = 0; fm < 4; ++fm) {
    const int mrow = m0 + wr * 64 + fm * 16 + lg * 4;
#pragma unroll
    for (int fn = 0; fn < 4; ++fn) {
      const int n = n0 + wc * 64 + fn * 16 + l15;
      if (n < NM1) {
#pragma unroll
        for (int j = 0; j < 4; ++j)
          out[(size_t)(mrow + j) * NM1 + n] = acc[fm][fn][j];
      }
    }
  }
}

extern "C" void kernel_launch(void* const* d_in, const int* in_sizes, int n_in,
                              void* d_out, int out_size, void* d_ws,
                              size_t ws_size, hipStream_t stream) {
  const int* inputs = (const int*)d_in[0];
  const float* masks = (const float*)d_in[1];
  const float* emb = (const float*)d_in[2];
  const float* Qw = (const float*)d_in[3];
  const float* Kw = (const float*)d_in[4];
  const float* lin_w = (const float*)d_in[5];
  const float* lin_b = (const float*)d_in[6];

  float* out_scores = (float*)d_out;                       // [B, N-1]
  float* out_aff = out_scores + (size_t)BB * NM1;          // [B, L, L]
  short* frb = (short*)d_ws;                               // [B, H] bf16, 512 KB

  session_kernel<<<dim3(BB), dim3(256), 0, stream>>>(
      inputs, masks, emb, Qw, Kw, lin_w, lin_b, out_aff, frb);

  scores_kernel<<<dim3(8 * NBLK), dim3(256), 0, stream>>>(frb, emb, out_scores);
}

// Round 2
// 814.075 us; speedup vs baseline: 1.6025x; 1.1220x over previous
//
#include <hip/hip_runtime.h>
#include <hip/hip_bf16.h>

#define BB 1024
#define LL 50
#define HH 256
#define AA 100
#define NN 100000
#define NM1 99999

typedef short short8 __attribute__((ext_vector_type(8)));
typedef float f32x4 __attribute__((ext_vector_type(4)));

__device__ __forceinline__ float wave_sum(float v) {
#pragma unroll
  for (int off = 32; off; off >>= 1) v += __shfl_xor(v, off, 64);
  return v;
}
__device__ __forceinline__ float wave_max(float v) {
#pragma unroll
  for (int off = 32; off; off >>= 1) v = fmaxf(v, __shfl_xor(v, off, 64));
  return v;
}
__device__ __forceinline__ short f2bf(float f) {
  union { __hip_bfloat16 h; short s; } u;
  u.h = __float2bfloat16(f);
  return u.s;
}
__device__ __forceinline__ float bf2f(short s) {
  union { short s; __hip_bfloat16 h; } u;
  u.s = s;
  return __bfloat162float(u.h);
}

// ---------------------------------------------------------------------------
// Kernel A: one block per session b. All matmul-shaped phases on MFMA:
//  1) logits[64(l),224(a')] = Xb[64,256] . Wcat[256,224]  (Q cols 0..111 from
//     Qw, K cols 112..223 from Kw; pads clamped+discarded)
//  2) affinity[64,64] = Qb[64,128] . Kb[64,128]^T  (a-dim zero-padded to 128)
// LDS tiles bf16, XOR-swizzled (byte ^= (row&7)<<4) so MFMA ds_read_b128 at
// 256/512B row stride is conflict-free. LDS ~69 KB -> 2 blocks/CU.
// ---------------------------------------------------------------------------
__global__ __launch_bounds__(256) void session_kernel(
    const int* __restrict__ inputs, const float* __restrict__ masks,
    const float* __restrict__ emb, const float* __restrict__ Qw,
    const float* __restrict__ Kw, const float* __restrict__ lin_w,
    const float* __restrict__ lin_b, float* __restrict__ out_aff,
    short* __restrict__ frb) {
  __shared__ short s_xb[64 * 256];   // 32 KB  x bf16, swizzled [l][h]
  __shared__ short s_q[64 * 128];    // 16 KB  Q bf16, swizzled [l][a] (pad 0)
  __shared__ short s_k[64 * 128];    // 16 KB  K bf16, swizzled [m][a] (pad 0)
  __shared__ float s_mask[64];
  __shared__ int s_idx[64];
  __shared__ float s_rowp[4][64];    // per-wave partial row sums
  __shared__ float s_p[64];
  __shared__ float s_cat[2 * HH];
  __shared__ int s_last;

  const int b = blockIdx.x;
  const int tid = threadIdx.x;
  const int lane = tid & 63;
  const int wv = tid >> 6;
  const int l15 = lane & 15;
  const int lg = lane >> 4;

  if (tid < 64) s_mask[tid] = (tid < LL) ? masks[b * LL + tid] : 0.f;
  if (tid < LL) s_idx[tid] = inputs[b * LL + tid];
  // zero Q/K buffers (pads must be 0 for the affinity K-dim)
#pragma unroll
  for (int i = 0; i < 4; ++i) {
    short8 z = {};
    ((short8*)s_q)[tid + i * 256] = z;
    ((short8*)s_k)[tid + i * 256] = z;
  }
  __syncthreads();

  // ---- gather x = emb[inputs[b]] -> bf16 swizzled LDS (rows >=50 unused) ---
  for (int u = tid; u < LL * 32; u += 256) {
    const int r = u >> 5, c = u & 31;
    const float* s = emb + (size_t)s_idx[r] * HH + c * 8;
    const float4 f0 = *(const float4*)s;
    const float4 f1 = *(const float4*)(s + 4);
    short8 v;
    v[0] = f2bf(f0.x); v[1] = f2bf(f0.y); v[2] = f2bf(f0.z); v[3] = f2bf(f0.w);
    v[4] = f2bf(f1.x); v[5] = f2bf(f1.y); v[6] = f2bf(f1.z); v[7] = f2bf(f1.w);
    const int byte = ((r << 9) | (c << 4)) ^ ((r & 7) << 4);
    *(short8*)((char*)s_xb + byte) = v;
  }
  __syncthreads();

  // ---- Q/K logits GEMM: wave wv owns N-frags {wv, wv+4, wv+8, wv+12} ------
  f32x4 acc[4][4];  // [nfi][mf]
#pragma unroll
  for (int i = 0; i < 4; ++i)
#pragma unroll
    for (int j = 0; j < 4; ++j) acc[i][j] = (f32x4)(0.f);

#pragma unroll
  for (int ks = 0; ks < 8; ++ks) {
    const int kb = (ks * 32 + lg * 8) * 2;
    short8 af[4];
#pragma unroll
    for (int mf = 0; mf < 4; ++mf) {
      const int r = mf * 16 + l15;
      af[mf] = *(const short8*)((const char*)s_xb +
                                (((r << 9) + kb) ^ ((r & 7) << 4)));
    }
#pragma unroll
    for (int nfi = 0; nfi < 4; ++nfi) {
      const int nf = wv + 4 * nfi;  // 0..15; 14,15 are dummy work (discarded)
      const float* Wp = (nf < 7) ? Qw : Kw;
      int arow = (nf < 7) ? nf * 16 + l15 : (nf - 7) * 16 + l15;
      if (nf >= 14) arow = 0;
      if (arow > AA - 1) arow = AA - 1;  // clamp: safe read, discarded result
      const float* s = Wp + (size_t)arow * HH + ks * 32 + lg * 8;
      const float4 w0 = *(const float4*)s;
      const float4 w1 = *(const float4*)(s + 4);
      short8 bf;
      bf[0] = f2bf(w0.x); bf[1] = f2bf(w0.y); bf[2] = f2bf(w0.z); bf[3] = f2bf(w0.w);
      bf[4] = f2bf(w1.x); bf[5] = f2bf(w1.y); bf[6] = f2bf(w1.z); bf[7] = f2bf(w1.w);
#pragma unroll
      for (int mf = 0; mf < 4; ++mf)
        acc[nfi][mf] =
            __builtin_amdgcn_mfma_f32_16x16x32_bf16(af[mf], bf, acc[nfi][mf], 0, 0, 0);
    }
  }
  // sigmoid -> bf16 Q/K in LDS (guards keep pads zero)
#pragma unroll
  for (int nfi = 0; nfi < 4; ++nfi) {
    const int nf = wv + 4 * nfi;
#pragma unroll
    for (int mf = 0; mf < 4; ++mf)
#pragma unroll
      for (int j = 0; j < 4; ++j) {
        const int row = mf * 16 + lg * 4 + j;
        const float sg = 1.f / (1.f + expf(-acc[nfi][mf][j]));
        if (row < LL && nf < 14) {
          if (nf < 7) {
            const int a = nf * 16 + l15;
            if (a < AA)
              *(short*)((char*)s_q + (((row << 8) + a * 2) ^ ((row & 7) << 4))) =
                  f2bf(sg);
          } else {
            const int a = (nf - 7) * 16 + l15;
            if (a < AA)
              *(short*)((char*)s_k + (((row << 8) + a * 2) ^ ((row & 7) << 4))) =
                  f2bf(sg);
          }
        }
      }
  }
  __syncthreads();

  // ---- affinity MFMA: wave wv owns m-cols [16*wv, 16*wv+16) ---------------
  f32x4 c4[4];
#pragma unroll
  for (int i = 0; i < 4; ++i) c4[i] = (f32x4)(0.f);
#pragma unroll
  for (int ks = 0; ks < 4; ++ks) {
    const int kb = (ks * 32 + lg * 8) * 2;
    const int mrow = wv * 16 + l15;
    const short8 kf = *(const short8*)((const char*)s_k +
                                       (((mrow << 8) + kb) ^ ((mrow & 7) << 4)));
#pragma unroll
    for (int mf = 0; mf < 4; ++mf) {
      const int r = mf * 16 + l15;
      const short8 qf = *(const short8*)((const char*)s_q +
                                         (((r << 8) + kb) ^ ((r & 7) << 4)));
      c4[mf] = __builtin_amdgcn_mfma_f32_16x16x32_bf16(qf, kf, c4[mf], 0, 0, 0);
    }
  }
  {
    const int col = wv * 16 + l15;
#pragma unroll
    for (int mf = 0; mf < 4; ++mf)
#pragma unroll
      for (int j = 0; j < 4; ++j) {
        const int row = mf * 16 + lg * 4 + j;
        const float val = c4[mf][j] * 0.1f;  // 1/sqrt(A)
        if (row < LL && col < LL)
          out_aff[(size_t)b * (LL * LL) + row * LL + col] = val;
        float am = (col < LL && col != row) ? val * s_mask[col] : 0.f;
        am += __shfl_xor(am, 1, 64);
        am += __shfl_xor(am, 2, 64);
        am += __shfl_xor(am, 4, 64);
        am += __shfl_xor(am, 8, 64);
        if (l15 == 0) s_rowp[wv][row] = am;
      }
  }
  __syncthreads();

  // ---- softmax over l (stable), mask, renormalize; last item id. One wave.
  if (tid < 64) {
    const int l = tid;
    const float mk = s_mask[l];
    float v = -3.4e38f;
    if (l < LL)
      v = (s_rowp[0][l] + s_rowp[1][l] + s_rowp[2][l] + s_rowp[3][l]) * mk;
    const float mx = wave_max(v);
    const float e = (l < LL) ? expf(v - mx) : 0.f;
    const float s1 = wave_sum(e);
    float p = e / s1 * mk;
    const float s2 = wave_sum(p);
    p /= s2;
    if (l < LL) s_p[l] = p;
    const float cnt = wave_sum(mk);
    if (l == 0) s_last = s_idx[(int)(cnt + 0.5f) - 1];
  }
  __syncthreads();

  // ---- att_final (weighted sum of bf16 x) + last_emb -> concat ------------
  {
    const int h = tid;
    float a = 0.f;
#pragma unroll
    for (int l = 0; l < LL; ++l) {
      const short xv = *(const short*)((const char*)s_xb +
                                       ((((l << 9) + h * 2)) ^ ((l & 7) << 4)));
      a += s_p[l] * bf2f(xv);
    }
    s_cat[h] = a;
    s_cat[HH + h] = emb[(size_t)s_last * HH + h];
  }
  __syncthreads();

  // ---- final_rep[h] = lin_b[h] + cat . lin_w[h,:]  -> BF16 workspace ------
  {
    const int h = tid;
    float acc2 = lin_b[h];
    const float4* lw = (const float4*)(lin_w + (size_t)h * (2 * HH));
#pragma unroll 16
    for (int j = 0; j < (2 * HH) / 4; ++j) {
      const float4 w = lw[j];
      const float4 cv = *(const float4*)&s_cat[j * 4];
      acc2 += w.x * cv.x + w.y * cv.y + w.z * cv.z + w.w * cv.w;
    }
    frb[(size_t)b * HH + h] = f2bf(acc2);
  }
}

// ---------------------------------------------------------------------------
// Kernel B: scores[m][n] = FR[m,:] . emb[1+n,:]   (M=1024, N=99999, K=256)
// BF16 MFMA GEMM, 128x128 tile, 4 waves (2x2), 4x4 frags of 16x16x32.
// K split into two 128-halves -> LDS 64 KB -> 2 blocks/CU so one block's
// staging overlaps the other's MFMA. XOR-swizzled LDS; XCD-chunked grid.
// ---------------------------------------------------------------------------
#define NBLK 782  // ceil(99999/128)
__global__ __launch_bounds__(256) void scores_kernel(
    const short* __restrict__ frb, const float* __restrict__ emb,
    float* __restrict__ out) {
  __shared__ short As[128 * 128];  // 32 KB, swizzled (K-half)
  __shared__ short Bs[128 * 128];  // 32 KB, swizzled

  const int tid = threadIdx.x;
  const int wg = blockIdx.x;
  // bijective XCD chunking: 6256 = 8 * 782; p runs m-fastest within an XCD
  const int p = (wg & 7) * NBLK + (wg >> 3);
  const int m0 = (p & 7) * 128;
  const int n0 = (p >> 3) * 128;

  const int lane = tid & 63;
  const int wv = tid >> 6;
  const int wr = wv >> 1, wc = wv & 1;  // 2x2 wave grid, each wave 64x64
  const int l15 = lane & 15, lg = lane >> 4;

  f32x4 acc[4][4];
#pragma unroll
  for (int fm = 0; fm < 4; ++fm)
#pragma unroll
    for (int fn = 0; fn < 4; ++fn) acc[fm][fn] = (f32x4)(0.f);

  for (int kh = 0; kh < 2; ++kh) {
    if (kh) __syncthreads();  // previous compute done before overwrite
#pragma unroll
    for (int i = 0; i < 8; ++i) {
      const int idx = tid + i * 256;
      const int r = idx >> 4, c = idx & 15;
      const int byte = ((r << 8) | (c << 4)) ^ ((r & 7) << 4);
      *(short8*)((char*)As + byte) =
          *(const short8*)(frb + (((size_t)(m0 + r)) << 8) + kh * 128 + (c << 3));
      int er = 1 + n0 + r;
      if (er > NM1) er = NM1;  // clamp: load valid, store guarded
      const float* s = emb + (((size_t)er) << 8) + kh * 128 + (c << 3);
      const float4 f0 = *(const float4*)s;
      const float4 f1 = *(const float4*)(s + 4);
      short8 v;
      v[0] = f2bf(f0.x); v[1] = f2bf(f0.y); v[2] = f2bf(f0.z); v[3] = f2bf(f0.w);
      v[4] = f2bf(f1.x); v[5] = f2bf(f1.y); v[6] = f2bf(f1.z); v[7] = f2bf(f1.w);
      *(short8*)((char*)Bs + byte) = v;
    }
    __syncthreads();
#pragma unroll
    for (int ks = 0; ks < 4; ++ks) {
      const int kb = ks * 64 + lg * 16;
      short8 af[4], bf[4];
#pragma unroll
      for (int f = 0; f < 4; ++f) {
        const int Ra = wr * 64 + f * 16 + l15;
        af[f] = *(const short8*)((const char*)As +
                                 (((Ra << 8) + kb) ^ ((Ra & 7) << 4)));
        const int Rb = wc * 64 + f * 16 + l15;
        bf[f] = *(const short8*)((const char*)Bs +
                                 (((Rb << 8) + kb) ^ ((Rb & 7) << 4)));
      }
#pragma unroll
      for (int fm = 0; fm < 4; ++fm)
#pragma unroll
        for (int fn = 0; fn < 4; ++fn)
          acc[fm][fn] = __builtin_amdgcn_mfma_f32_16x16x32_bf16(
              af[fm], bf[fn], acc[fm][fn], 0, 0, 0);
    }
  }

  // ---- epilogue: C/D layout col=lane&15, row=(lane>>4)*4+reg ----
#pragma unroll
  for (int fm = 0; fm < 4; ++fm) {
    const int mrow = m0 + wr * 64 + fm * 16 + lg * 4;
#pragma unroll
    for (int fn = 0; fn < 4; ++fn) {
      const int n = n0 + wc * 64 + fn * 16 + l15;
      if (n < NM1) {
#pragma unroll
        for (int j = 0; j < 4; ++j)
          out[(size_t)(mrow + j) * NM1 + n] = acc[fm][fn][j];
      }
    }
  }
}

extern "C" void kernel_launch(void* const* d_in, const int* in_sizes, int n_in,
                              void* d_out, int out_size, void* d_ws,
                              size_t ws_size, hipStream_t stream) {
  const int* inputs = (const int*)d_in[0];
  const float* masks = (const float*)d_in[1];
  const float* emb = (const float*)d_in[2];
  const float* Qw = (const float*)d_in[3];
  const float* Kw = (const float*)d_in[4];
  const float* lin_w = (const float*)d_in[5];
  const float* lin_b = (const float*)d_in[6];

  float* out_scores = (float*)d_out;                       // [B, N-1]
  float* out_aff = out_scores + (size_t)BB * NM1;          // [B, L, L]
  short* frb = (short*)d_ws;                               // [B, H] bf16

  session_kernel<<<dim3(BB), dim3(256), 0, stream>>>(
      inputs, masks, emb, Qw, Kw, lin_w, lin_b, out_aff, frb);

  scores_kernel<<<dim3(8 * NBLK), dim3(256), 0, stream>>>(frb, emb, out_scores);
}

// Round 5
// 800.431 us; speedup vs baseline: 1.6298x; 1.0170x over previous
//
#include <hip/hip_runtime.h>
#include <hip/hip_bf16.h>

#define BB 1024
#define LL 50
#define HH 256
#define AA 100
#define NN 100000
#define NM1 99999
#define NPAD 100096  // 782 tiles * 128

typedef short short8 __attribute__((ext_vector_type(8)));
typedef float f32x4 __attribute__((ext_vector_type(4)));

__device__ __forceinline__ float wave_sum(float v) {
#pragma unroll
  for (int off = 32; off; off >>= 1) v += __shfl_xor(v, off, 64);
  return v;
}
__device__ __forceinline__ float wave_max(float v) {
#pragma unroll
  for (int off = 32; off; off >>= 1) v = fmaxf(v, __shfl_xor(v, off, 64));
  return v;
}
__device__ __forceinline__ short f2bf(float f) {
  union { __hip_bfloat16 h; short s; } u;
  u.h = __float2bfloat16(f);
  return u.s;
}
__device__ __forceinline__ float bf2f(short s) {
  union { short s; __hip_bfloat16 h; } u;
  u.s = s;
  return __bfloat162float(u.h);
}

// ---------------------------------------------------------------------------
// Kernel A: one block per session b. MFMA for Q/K logits and affinity.
// Tail: grid-stride fp32->bf16 conversion of emb into embb [NPAD,256]
// (embb[r] = bf16(emb[min(r+1,NM1)])) — hides under this kernel's latency
// slack (its memory pipes are ~98% idle). Skipped if embb == nullptr.
// ---------------------------------------------------------------------------
__global__ __launch_bounds__(256) void session_kernel(
    const int* __restrict__ inputs, const float* __restrict__ masks,
    const float* __restrict__ emb, const float* __restrict__ Qw,
    const float* __restrict__ Kw, const float* __restrict__ lin_w,
    const float* __restrict__ lin_b, float* __restrict__ out_aff,
    short* __restrict__ frb, short* __restrict__ embb) {
  __shared__ short s_xb[64 * 256];   // 32 KB  x bf16, swizzled [l][h]
  __shared__ short s_q[64 * 128];    // 16 KB  Q bf16, swizzled [l][a] (pad 0)
  __shared__ short s_k[64 * 128];    // 16 KB  K bf16, swizzled [m][a] (pad 0)
  __shared__ float s_mask[64];
  __shared__ int s_idx[64];
  __shared__ float s_rowp[4][64];    // per-wave partial row sums
  __shared__ float s_p[64];
  __shared__ float s_cat[2 * HH];
  __shared__ int s_last;

  const int b = blockIdx.x;
  const int tid = threadIdx.x;
  const int lane = tid & 63;
  const int wv = tid >> 6;
  const int l15 = lane & 15;
  const int lg = lane >> 4;

  if (tid < 64) s_mask[tid] = (tid < LL) ? masks[b * LL + tid] : 0.f;
  if (tid < LL) s_idx[tid] = inputs[b * LL + tid];
  // zero Q/K buffers (pads must be 0 for the affinity K-dim)
#pragma unroll
  for (int i = 0; i < 4; ++i) {
    short8 z = {};
    ((short8*)s_q)[tid + i * 256] = z;
    ((short8*)s_k)[tid + i * 256] = z;
  }
  __syncthreads();

  // ---- gather x = emb[inputs[b]] -> bf16 swizzled LDS (rows >=50 unused) ---
  for (int u = tid; u < LL * 32; u += 256) {
    const int r = u >> 5, c = u & 31;
    const float* s = emb + (size_t)s_idx[r] * HH + c * 8;
    const float4 f0 = *(const float4*)s;
    const float4 f1 = *(const float4*)(s + 4);
    short8 v;
    v[0] = f2bf(f0.x); v[1] = f2bf(f0.y); v[2] = f2bf(f0.z); v[3] = f2bf(f0.w);
    v[4] = f2bf(f1.x); v[5] = f2bf(f1.y); v[6] = f2bf(f1.z); v[7] = f2bf(f1.w);
    const int byte = ((r << 9) | (c << 4)) ^ ((r & 7) << 4);
    *(short8*)((char*)s_xb + byte) = v;
  }
  __syncthreads();

  // ---- Q/K logits GEMM: wave wv owns N-frags {wv, wv+4, wv+8, wv+12} ------
  f32x4 acc[4][4];  // [nfi][mf]
#pragma unroll
  for (int i = 0; i < 4; ++i)
#pragma unroll
    for (int j = 0; j < 4; ++j) acc[i][j] = (f32x4)(0.f);

#pragma unroll
  for (int ks = 0; ks < 8; ++ks) {
    const int kb = (ks * 32 + lg * 8) * 2;
    short8 af[4];
#pragma unroll
    for (int mf = 0; mf < 4; ++mf) {
      const int r = mf * 16 + l15;
      af[mf] = *(const short8*)((const char*)s_xb +
                                (((r << 9) + kb) ^ ((r & 7) << 4)));
    }
#pragma unroll
    for (int nfi = 0; nfi < 4; ++nfi) {
      const int nf = wv + 4 * nfi;  // 0..15; 14,15 are dummy work (discarded)
      const float* Wp = (nf < 7) ? Qw : Kw;
      int arow = (nf < 7) ? nf * 16 + l15 : (nf - 7) * 16 + l15;
      if (nf >= 14) arow = 0;
      if (arow > AA - 1) arow = AA - 1;  // clamp: safe read, discarded result
      const float* s = Wp + (size_t)arow * HH + ks * 32 + lg * 8;
      const float4 w0 = *(const float4*)s;
      const float4 w1 = *(const float4*)(s + 4);
      short8 bf;
      bf[0] = f2bf(w0.x); bf[1] = f2bf(w0.y); bf[2] = f2bf(w0.z); bf[3] = f2bf(w0.w);
      bf[4] = f2bf(w1.x); bf[5] = f2bf(w1.y); bf[6] = f2bf(w1.z); bf[7] = f2bf(w1.w);
#pragma unroll
      for (int mf = 0; mf < 4; ++mf)
        acc[nfi][mf] =
            __builtin_amdgcn_mfma_f32_16x16x32_bf16(af[mf], bf, acc[nfi][mf], 0, 0, 0);
    }
  }
  // sigmoid -> bf16 Q/K in LDS (guards keep pads zero)
#pragma unroll
  for (int nfi = 0; nfi < 4; ++nfi) {
    const int nf = wv + 4 * nfi;
#pragma unroll
    for (int mf = 0; mf < 4; ++mf)
#pragma unroll
      for (int j = 0; j < 4; ++j) {
        const int row = mf * 16 + lg * 4 + j;
        const float sg = 1.f / (1.f + expf(-acc[nfi][mf][j]));
        if (row < LL && nf < 14) {
          if (nf < 7) {
            const int a = nf * 16 + l15;
            if (a < AA)
              *(short*)((char*)s_q + (((row << 8) + a * 2) ^ ((row & 7) << 4))) =
                  f2bf(sg);
          } else {
            const int a = (nf - 7) * 16 + l15;
            if (a < AA)
              *(short*)((char*)s_k + (((row << 8) + a * 2) ^ ((row & 7) << 4))) =
                  f2bf(sg);
          }
        }
      }
  }
  __syncthreads();

  // ---- affinity MFMA: wave wv owns m-cols [16*wv, 16*wv+16) ---------------
  f32x4 c4[4];
#pragma unroll
  for (int i = 0; i < 4; ++i) c4[i] = (f32x4)(0.f);
#pragma unroll
  for (int ks = 0; ks < 4; ++ks) {
    const int kb = (ks * 32 + lg * 8) * 2;
    const int mrow = wv * 16 + l15;
    const short8 kf = *(const short8*)((const char*)s_k +
                                       (((mrow << 8) + kb) ^ ((mrow & 7) << 4)));
#pragma unroll
    for (int mf = 0; mf < 4; ++mf) {
      const int r = mf * 16 + l15;
      const short8 qf = *(const short8*)((const char*)s_q +
                                         (((r << 8) + kb) ^ ((r & 7) << 4)));
      c4[mf] = __builtin_amdgcn_mfma_f32_16x16x32_bf16(qf, kf, c4[mf], 0, 0, 0);
    }
  }
  {
    const int col = wv * 16 + l15;
#pragma unroll
    for (int mf = 0; mf < 4; ++mf)
#pragma unroll
      for (int j = 0; j < 4; ++j) {
        const int row = mf * 16 + lg * 4 + j;
        const float val = c4[mf][j] * 0.1f;  // 1/sqrt(A)
        if (row < LL && col < LL)
          out_aff[(size_t)b * (LL * LL) + row * LL + col] = val;
        float am = (col < LL && col != row) ? val * s_mask[col] : 0.f;
        am += __shfl_xor(am, 1, 64);
        am += __shfl_xor(am, 2, 64);
        am += __shfl_xor(am, 4, 64);
        am += __shfl_xor(am, 8, 64);
        if (l15 == 0) s_rowp[wv][row] = am;
      }
  }
  __syncthreads();

  // ---- softmax over l (stable), mask, renormalize; last item id. One wave.
  if (tid < 64) {
    const int l = tid;
    const float mk = s_mask[l];
    float v = -3.4e38f;
    if (l < LL)
      v = (s_rowp[0][l] + s_rowp[1][l] + s_rowp[2][l] + s_rowp[3][l]) * mk;
    const float mx = wave_max(v);
    const float e = (l < LL) ? expf(v - mx) : 0.f;
    const float s1 = wave_sum(e);
    float p = e / s1 * mk;
    const float s2 = wave_sum(p);
    p /= s2;
    if (l < LL) s_p[l] = p;
    const float cnt = wave_sum(mk);
    if (l == 0) s_last = s_idx[(int)(cnt + 0.5f) - 1];
  }
  __syncthreads();

  // ---- att_final (weighted sum of bf16 x) + last_emb -> concat ------------
  {
    const int h = tid;
    float a = 0.f;
#pragma unroll
    for (int l = 0; l < LL; ++l) {
      const short xv = *(const short*)((const char*)s_xb +
                                       ((((l << 9) + h * 2)) ^ ((l & 7) << 4)));
      a += s_p[l] * bf2f(xv);
    }
    s_cat[h] = a;
    s_cat[HH + h] = emb[(size_t)s_last * HH + h];
  }
  __syncthreads();

  // ---- final_rep[h] = lin_b[h] + cat . lin_w[h,:]  -> BF16 workspace ------
  {
    const int h = tid;
    float acc2 = lin_b[h];
    const float4* lw = (const float4*)(lin_w + (size_t)h * (2 * HH));
#pragma unroll 16
    for (int j = 0; j < (2 * HH) / 4; ++j) {
      const float4 w = lw[j];
      const float4 cv = *(const float4*)&s_cat[j * 4];
      acc2 += w.x * cv.x + w.y * cv.y + w.z * cv.z + w.w * cv.w;
    }
    frb[(size_t)b * HH + h] = f2bf(acc2);
  }

  // ---- tail: convert emb -> embb bf16 [NPAD,256], grid-stride ------------
  if (embb) {
    const size_t total = (size_t)NPAD * 32;  // 8-float units
    for (size_t u = (size_t)b * 256 + tid; u < total; u += (size_t)BB * 256) {
      const int r = (int)(u >> 5), c = (int)(u & 31);
      int er = r + 1;
      if (er > NM1) er = NM1;
      const float* s = emb + (size_t)er * HH + c * 8;
      const float4 f0 = *(const float4*)s;
      const float4 f1 = *(const float4*)(s + 4);
      short8 v;
      v[0] = f2bf(f0.x); v[1] = f2bf(f0.y); v[2] = f2bf(f0.z); v[3] = f2bf(f0.w);
      v[4] = f2bf(f1.x); v[5] = f2bf(f1.y); v[6] = f2bf(f1.z); v[7] = f2bf(f1.w);
      *(short8*)(embb + (((size_t)r) << 8) + c * 8) = v;
    }
  }
}

// ---------------------------------------------------------------------------
// Kernel B (new): barrier-free streaming GEMM. A panel (64 m-rows x 256 K
// per wave = 128 VGPR bf16) loaded ONCE into registers; block then streams
// TTILES n-tiles: {B-frags direct global->reg from pre-converted bf16 emb,
// MFMA, store}. No LDS, no __syncthreads -> pure ILP/TLP latency hiding.
// Grid mapping: chunk cg has cg%8 == xcd so the 8 m-blocks sharing a B
// chunk land on one XCD (B stays L2-resident there).
// ---------------------------------------------------------------------------
#define NBLK 782    // ceil(99999/128)
#define TTILES 4
#define NCHUNK 196  // ceil(782/4)
__global__ __launch_bounds__(256, 2) void scores_stream(
    const short* __restrict__ frb, const short* __restrict__ embb,
    float* __restrict__ out) {
  const int tid = threadIdx.x;
  const int bid = blockIdx.x;
  const int xcd = bid & 7;
  const int j = bid >> 3;                 // 0..199
  const int cg = (j >> 3) * 8 + xcd;      // chunk id, cg%8 == xcd
  if (cg >= NCHUNK) return;
  const int m0 = (j & 7) * 128;

  const int lane = tid & 63;
  const int wv = tid >> 6;
  const int wr = wv >> 1, wc = wv & 1;    // 2x2 wave grid, wave = 64m x 64n
  const int l15 = lane & 15, lg = lane >> 4;

  // ---- A panel into registers: frags [fm][ks], 128 VGPR ----
  short8 af[4][8];
#pragma unroll
  for (int fm = 0; fm < 4; ++fm) {
    const short* ap =
        frb + (((size_t)(m0 + wr * 64 + fm * 16 + l15)) << 8) + lg * 8;
#pragma unroll
    for (int ks = 0; ks < 8; ++ks) af[fm][ks] = *(const short8*)(ap + ks * 32);
  }

  for (int t = 0; t < TTILES; ++t) {
    const int nt = cg * TTILES + t;
    if (nt >= NBLK) break;
    const int n0 = nt * 128;
    const short* bp =
        embb + (((size_t)(n0 + wc * 64 + l15)) << 8) + lg * 8;

    f32x4 acc[4][4];
#pragma unroll
    for (int fm = 0; fm < 4; ++fm)
#pragma unroll
      for (int fn = 0; fn < 4; ++fn) acc[fm][fn] = (f32x4)(0.f);

#pragma unroll
    for (int ks = 0; ks < 8; ++ks) {
      short8 bf[4];
#pragma unroll
      for (int fn = 0; fn < 4; ++fn)
        bf[fn] = *(const short8*)(bp + ((size_t)fn << 12) + ks * 32);
#pragma unroll
      for (int fm = 0; fm < 4; ++fm)
#pragma unroll
        for (int fn = 0; fn < 4; ++fn)
          acc[fm][fn] = __builtin_amdgcn_mfma_f32_16x16x32_bf16(
              af[fm][ks], bf[fn], acc[fm][fn], 0, 0, 0);
    }

    // ---- epilogue: C/D layout col=lane&15, row=(lane>>4)*4+reg ----
#pragma unroll
    for (int fm = 0; fm < 4; ++fm) {
      const int mrow = m0 + wr * 64 + fm * 16 + lg * 4;
#pragma unroll
      for (int fn = 0; fn < 4; ++fn) {
        const int n = n0 + wc * 64 + fn * 16 + l15;
        if (n < NM1) {
#pragma unroll
          for (int jj = 0; jj < 4; ++jj)
            out[(size_t)(mrow + jj) * NM1 + n] = acc[fm][fn][jj];
        }
      }
    }
  }
}

// ---------------------------------------------------------------------------
// Kernel B (fallback, ws too small): round-2 LDS-staged MFMA GEMM.
// ---------------------------------------------------------------------------
__global__ __launch_bounds__(256) void scores_kernel(
    const short* __restrict__ frb, const float* __restrict__ emb,
    float* __restrict__ out) {
  __shared__ short As[128 * 128];
  __shared__ short Bs[128 * 128];

  const int tid = threadIdx.x;
  const int wg = blockIdx.x;
  const int p = (wg & 7) * NBLK + (wg >> 3);
  const int m0 = (p & 7) * 128;
  const int n0 = (p >> 3) * 128;

  const int lane = tid & 63;
  const int wv = tid >> 6;
  const int wr = wv >> 1, wc = wv & 1;
  const int l15 = lane & 15, lg = lane >> 4;

  f32x4 acc[4][4];
#pragma unroll
  for (int fm = 0; fm < 4; ++fm)
#pragma unroll
    for (int fn = 0; fn < 4; ++fn) acc[fm][fn] = (f32x4)(0.f);

  for (int kh = 0; kh < 2; ++kh) {
    if (kh) __syncthreads();
#pragma unroll
    for (int i = 0; i < 8; ++i) {
      const int idx = tid + i * 256;
      const int r = idx >> 4, c = idx & 15;
      const int byte = ((r << 8) | (c << 4)) ^ ((r & 7) << 4);
      *(short8*)((char*)As + byte) =
          *(const short8*)(frb + (((size_t)(m0 + r)) << 8) + kh * 128 + (c << 3));
      int er = 1 + n0 + r;
      if (er > NM1) er = NM1;
      const float* s = emb + (((size_t)er) << 8) + kh * 128 + (c << 3);
      const float4 f0 = *(const float4*)s;
      const float4 f1 = *(const float4*)(s + 4);
      short8 v;
      v[0] = f2bf(f0.x); v[1] = f2bf(f0.y); v[2] = f2bf(f0.z); v[3] = f2bf(f0.w);
      v[4] = f2bf(f1.x); v[5] = f2bf(f1.y); v[6] = f2bf(f1.z); v[7] = f2bf(f1.w);
      *(short8*)((char*)Bs + byte) = v;
    }
    __syncthreads();
#pragma unroll
    for (int ks = 0; ks < 4; ++ks) {
      const int kb = ks * 64 + lg * 16;
      short8 af[4], bf[4];
#pragma unroll
      for (int f = 0; f < 4; ++f) {
        const int Ra = wr * 64 + f * 16 + l15;
        af[f] = *(const short8*)((const char*)As +
                                 (((Ra << 8) + kb) ^ ((Ra & 7) << 4)));
        const int Rb = wc * 64 + f * 16 + l15;
        bf[f] = *(const short8*)((const char*)Bs +
                                 (((Rb << 8) + kb) ^ ((Rb & 7) << 4)));
      }
#pragma unroll
      for (int fm = 0; fm < 4; ++fm)
#pragma unroll
        for (int fn = 0; fn < 4; ++fn)
          acc[fm][fn] = __builtin_amdgcn_mfma_f32_16x16x32_bf16(
              af[fm], bf[fn], acc[fm][fn], 0, 0, 0);
    }
  }

#pragma unroll
  for (int fm = 0; fm < 4; ++fm) {
    const int mrow = m0 + wr * 64 + fm * 16 + lg * 4;
#pragma unroll
    for (int fn = 0; fn < 4; ++fn) {
      const int n = n0 + wc * 64 + fn * 16 + l15;
      if (n < NM1) {
#pragma unroll
        for (int j = 0; j < 4; ++j)
          out[(size_t)(mrow + j) * NM1 + n] = acc[fm][fn][j];
      }
    }
  }
}

extern "C" void kernel_launch(void* const* d_in, const int* in_sizes, int n_in,
                              void* d_out, int out_size, void* d_ws,
                              size_t ws_size, hipStream_t stream) {
  const int* inputs = (const int*)d_in[0];
  const float* masks = (const float*)d_in[1];
  const float* emb = (const float*)d_in[2];
  const float* Qw = (const float*)d_in[3];
  const float* Kw = (const float*)d_in[4];
  const float* lin_w = (const float*)d_in[5];
  const float* lin_b = (const float*)d_in[6];

  float* out_scores = (float*)d_out;              // [B, N-1]
  float* out_aff = out_scores + (size_t)BB * NM1; // [B, L, L]
  short* frb = (short*)d_ws;                      // [B, H] bf16, 512 KB

  const size_t need =
      (size_t)BB * HH * 2 + (size_t)NPAD * HH * 2;  // frb + embb
  short* embb = (ws_size >= need) ? frb + (size_t)BB * HH : nullptr;

  session_kernel<<<dim3(BB), dim3(256), 0, stream>>>(
      inputs, masks, emb, Qw, Kw, lin_w, lin_b, out_aff, frb, embb);

  if (embb) {
    scores_stream<<<dim3(1600), dim3(256), 0, stream>>>(frb, embb, out_scores);
  } else {
    scores_kernel<<<dim3(8 * NBLK), dim3(256), 0, stream>>>(frb, emb,
                                                            out_scores);
  }
}